// Round 6
// baseline (114.661 us; speedup 1.0000x reference)
//
#include <hip/hip_runtime.h>
#include <math.h>

#define B    64
#define DQ   512
#define DO   256
#define NH   8
#define DH   32
#define HW   1024
#define NCH  16     // s-chunks per image
#define CHS  64     // s per chunk

// ---------------------------------------------------------------- k1: qv = q @ w_q.T + b_q   (wave-per-output GEMV)
__global__ __launch_bounds__(256) void k1_qv(const float* __restrict__ q,
                                             const float* __restrict__ w_q,
                                             const float* __restrict__ b_q,
                                             float* __restrict__ qv) {
    int cg = blockIdx.x, b = blockIdx.y;
    int t = threadIdx.x;
    int wid = t >> 6, lane = t & 63;
    const float4* qrow = reinterpret_cast<const float4*>(q + (size_t)b*DQ);
    float4 q0 = qrow[lane*2], q1 = qrow[lane*2 + 1];
    #pragma unroll
    for (int r = 0; r < 4; ++r) {
        int c = cg*16 + wid*4 + r;
        const float4* wrow = reinterpret_cast<const float4*>(w_q + (size_t)c*DQ);
        float4 w0 = wrow[lane*2], w1 = wrow[lane*2 + 1];
        float acc = q0.x*w0.x + q0.y*w0.y + q0.z*w0.z + q0.w*w0.w
                  + q1.x*w1.x + q1.y*w1.y + q1.z*w1.z + q1.w*w1.w;
        #pragma unroll
        for (int k = 32; k > 0; k >>= 1) acc += __shfl_xor(acc, k);
        if (lane == 0) qv[b*DO + c] = acc + b_q[c];
    }
}

// ---------------------------------------------------------------- k2: fold qv into kc/kd weights
__global__ void k2_wqk(const float* __restrict__ qv,
                       const float* __restrict__ w_kc, const float* __restrict__ b_kc,
                       const float* __restrict__ w_kd, const float* __restrict__ b_kd,
                       const float* __restrict__ temp_c, const float* __restrict__ temp_d,
                       float* __restrict__ wqkc, float* __restrict__ wqkd,
                       float* __restrict__ qbc, float* __restrict__ qbd) {
    int bn = blockIdx.x;              // b*8 + n
    int n  = bn & 7;
    int t  = threadIdx.x;             // c
    __shared__ float qvs[DH];
    if (t < DH) qvs[t] = qv[(bn >> 3)*DO + n*DH + t];
    __syncthreads();
    float itc = 1.0f / temp_c[0];
    float itd = 1.0f / temp_d[0];
    float ac = 0.f, ad = 0.f;
    #pragma unroll
    for (int d = 0; d < DH; ++d) {
        float qd = qvs[d];
        ac += qd * w_kc[(n*DH + d)*DO + t];
        ad += qd * w_kd[(n*DH + d)*DO + t];
    }
    wqkc[bn*DO + t] = ac * itc;
    wqkd[bn*DO + t] = ad * itd;
    if (t == 0) {
        float sc = 0.f;
        for (int d = 0; d < DH; ++d) sc += qvs[d]*b_kc[n*DH + d];
        qbc[bn] = sc * itc;
    }
    if (t == 1) {
        float sd = 0.f;
        for (int d = 0; d < DH; ++d) sd += qvs[d]*b_kd[n*DH + d];
        qbd[bn] = sd * itd;
    }
}

// ---------------------------------------------------------------- k3: logits + gate + block-local softmax stats
__global__ __launch_bounds__(512, 8)
void k3(const float* __restrict__ v,
        const float* __restrict__ wqkc, const float* __restrict__ wqkd,
        const float* __restrict__ qbc,  const float* __restrict__ qbd,
        float* __restrict__ gate, float* __restrict__ ebuf, float* __restrict__ mz) {
    __shared__ float pc[8*NH*CHS];   // 16 KB
    __shared__ float pd[8*NH*CHS];   // 16 KB
    int ch = blockIdx.x, b = blockIdx.y;
    int t  = threadIdx.x;
    int s0 = ch*CHS;
    int bn0 = b*NH;
    int sl = t & 63;
    int csub = __builtin_amdgcn_readfirstlane(t >> 6);

    {
        const float* vb = v + (size_t)b*DO*HW + s0 + sl;
        const float* wc = wqkc + bn0*DO;
        const float* wd = wqkd + bn0*DO;
        float ac[NH] = {0,0,0,0,0,0,0,0};
        float ad[NH] = {0,0,0,0,0,0,0,0};
        int cbase = csub*32;
        for (int c0 = cbase; c0 < cbase + 32; c0 += 4) {
            float v0 = vb[(size_t)(c0+0)*HW];
            float v1 = vb[(size_t)(c0+1)*HW];
            float v2 = vb[(size_t)(c0+2)*HW];
            float v3 = vb[(size_t)(c0+3)*HW];
            #pragma unroll
            for (int n = 0; n < NH; ++n) {
                ac[n] += v0*wc[n*DO+c0] + v1*wc[n*DO+c0+1] + v2*wc[n*DO+c0+2] + v3*wc[n*DO+c0+3];
                ad[n] += v0*wd[n*DO+c0] + v1*wd[n*DO+c0+1] + v2*wd[n*DO+c0+2] + v3*wd[n*DO+c0+3];
            }
        }
        #pragma unroll
        for (int n = 0; n < NH; ++n) {
            pc[(csub*NH + n)*CHS + sl] = ac[n];
            pd[(csub*NH + n)*CHS + sl] = ad[n];
        }
    }
    __syncthreads();

    {
        int n = csub, s = sl;
        float lc = qbc[bn0+n], ld = qbd[bn0+n];
        #pragma unroll
        for (int k = 0; k < 8; ++k) {
            lc += pc[(k*NH + n)*CHS + s];
            ld += pd[(k*NH + n)*CHS + s];
        }
        gate[(bn0+n)*HW + s0 + s] = 1.0f/(1.0f + __expf(-ld));
        float m = lc;
        #pragma unroll
        for (int k = 32; k > 0; k >>= 1) m = fmaxf(m, __shfl_xor(m, k));
        float e = __expf(lc - m);
        ebuf[(bn0+n)*HW + s0 + s] = e;
        float z = e;
        #pragma unroll
        for (int k = 32; k > 0; k >>= 1) z += __shfl_xor(z, k);
        if (s == 0) {
            float* mzp = mz + ((size_t)(b*NCH + ch)*NH + n)*2;
            mzp[0] = m; mzp[1] = z;
        }
    }
}

// ---------------------------------------------------------------- kPp: partial normalized pool over 256-s slices
// grid (8 cg, 4 sq, B), block 256 (4 waves). pvp[b][sq][n][c]
__global__ __launch_bounds__(256) void kPp(const float* __restrict__ v,
                                           const float* __restrict__ ebuf,
                                           const float* __restrict__ mz,
                                           float* __restrict__ pvp) {
    __shared__ float p_lds[NH][256];     // 8 KB normalized probs for this s-slice
    __shared__ float scale_l[4*NH];      // scales for the 4 64-chunks inside the slice
    int cg = blockIdx.x, sq = blockIdx.y, b = blockIdx.z;
    int t = threadIdx.x;
    if (t < NH) {
        int n = t;
        float M = -1e30f;
        for (int ch = 0; ch < NCH; ++ch)
            M = fmaxf(M, mz[((size_t)(b*NCH+ch)*NH+n)*2]);
        float Z = 0.f;
        for (int ch = 0; ch < NCH; ++ch)
            Z += __expf(mz[((size_t)(b*NCH+ch)*NH+n)*2] - M) * mz[((size_t)(b*NCH+ch)*NH+n)*2+1];
        float inv = 1.0f/Z;
        #pragma unroll
        for (int k = 0; k < 4; ++k) {
            int ch = sq*4 + k;
            scale_l[k*NH+n] = __expf(mz[((size_t)(b*NCH+ch)*NH+n)*2] - M) * inv;
        }
    }
    __syncthreads();
    {   // stage normalized p: NH*256 = 2048 floats; 8 per thread (one 64-chunk-aligned pair of float4)
        int g = t*8;
        int n = g >> 8, so = g & 255;
        float sc = scale_l[(so>>6)*NH + n];
        const float* eb = ebuf + (size_t)(b*NH+n)*HW + sq*256 + so;
        float4 e0 = *reinterpret_cast<const float4*>(eb);
        float4 e1 = *reinterpret_cast<const float4*>(eb + 4);
        *reinterpret_cast<float4*>(&p_lds[n][so])   = make_float4(e0.x*sc, e0.y*sc, e0.z*sc, e0.w*sc);
        *reinterpret_cast<float4*>(&p_lds[n][so+4]) = make_float4(e1.x*sc, e1.y*sc, e1.z*sc, e1.w*sc);
    }
    __syncthreads();
    int wid = t >> 6, lane = t & 63;
    #pragma unroll
    for (int r = 0; r < 8; ++r) {
        int c = cg*32 + wid*8 + r;
        float4 v4 = *reinterpret_cast<const float4*>(v + ((size_t)(b*DO+c))*HW + sq*256 + lane*4);
        float red[NH];
        #pragma unroll
        for (int n = 0; n < NH; ++n) {
            float4 p4 = *reinterpret_cast<const float4*>(&p_lds[n][lane*4]);
            red[n] = v4.x*p4.x + v4.y*p4.y + v4.z*p4.z + v4.w*p4.w;
        }
        #pragma unroll
        for (int n = 0; n < NH; ++n) {
            float x = red[n];
            #pragma unroll
            for (int k = 32; k > 0; k >>= 1) x += __shfl_xor(x, k);
            red[n] = x;
        }
        if (lane == 0) {
            #pragma unroll
            for (int n = 0; n < NH; ++n)
                pvp[((size_t)(b*4+sq)*NH+n)*DO + c] = red[n];
        }
    }
}

// ---------------------------------------------------------------- k4c: sum sq-partials + attn = w_v . P + b_v
__global__ void k4c(const float* __restrict__ pvp, const float* __restrict__ w_v,
                    const float* __restrict__ b_v, float* __restrict__ attn) {
    __shared__ float pv_lds[NH*DO];
    int b = blockIdx.x, t = threadIdx.x;
    for (int i = t; i < NH*DO; i += 256) {
        float s = 0.f;
        #pragma unroll
        for (int sq = 0; sq < 4; ++sq) s += pvp[(size_t)(b*4+sq)*NH*DO + i];
        pv_lds[i] = s;
    }
    __syncthreads();
    int n = t >> 5;
    float acc = b_v[t];
    const float4* w4 = reinterpret_cast<const float4*>(w_v + t*DO);
    #pragma unroll 4
    for (int c4 = 0; c4 < DO/4; ++c4) {
        float4 wv = w4[c4];
        int c = c4*4;
        acc += pv_lds[n*DO+c]*wv.x + pv_lds[n*DO+c+1]*wv.y + pv_lds[n*DO+c+2]*wv.z + pv_lds[n*DO+c+3]*wv.w;
    }
    attn[b*DO + t] = acc;
}

// ---------------------------------------------------------------- k5: out = leaky(bn(gate[s^T]*attn + v))
__global__ void k5_out(const float* __restrict__ v, const float* __restrict__ gate,
                       const float* __restrict__ attn,
                       const float* __restrict__ bn_g, const float* __restrict__ bn_b,
                       const float* __restrict__ bn_m, const float* __restrict__ bn_v,
                       float* __restrict__ out) {
    int c = blockIdx.x, b = blockIdx.y;
    int n = c >> 5, d = c & 31;
    int t = threadIdx.x;
    __shared__ float g[32*33];             // stride 33 kills transpose bank conflicts
    float4 gv = reinterpret_cast<const float4*>(gate + (b*NH + n)*HW)[t];
    int s0 = t*4;
    int ga = s0 >> 5, gb = s0 & 31;
    g[ga*33 + gb + 0] = gv.x;
    g[ga*33 + gb + 1] = gv.y;
    g[ga*33 + gb + 2] = gv.z;
    g[ga*33 + gb + 3] = gv.w;
    __syncthreads();
    float av   = attn[(b*NH + n)*DH + d];
    float inv  = bn_g[c] / sqrtf(bn_v[c] + 1e-5f);
    float mean = bn_m[c], beta = bn_b[c];
    size_t base = ((size_t)(b*DO + c))*HW;
    float4 r4 = reinterpret_cast<const float4*>(v + base)[t];
    int l = 4*t;
    int i_ = l >> 5, j_ = l & 31;          // gate index s = j*32 + i
    float x0 = g[(j_+0)*33 + i_]*av + r4.x;
    float x1 = g[(j_+1)*33 + i_]*av + r4.y;
    float x2 = g[(j_+2)*33 + i_]*av + r4.z;
    float x3 = g[(j_+3)*33 + i_]*av + r4.w;
    float y0 = (x0 - mean)*inv + beta; y0 = y0 >= 0.f ? y0 : 0.1f*y0;
    float y1 = (x1 - mean)*inv + beta; y1 = y1 >= 0.f ? y1 : 0.1f*y1;
    float y2 = (x2 - mean)*inv + beta; y2 = y2 >= 0.f ? y2 : 0.1f*y2;
    float y3 = (x3 - mean)*inv + beta; y3 = y3 >= 0.f ? y3 : 0.1f*y3;
    reinterpret_cast<float4*>(out + base)[t] = make_float4(y0, y1, y2, y3);
}

// ----------------------------------------------------------------
extern "C" void kernel_launch(void* const* d_in, const int* in_sizes, int n_in,
                              void* d_out, int out_size, void* d_ws, size_t ws_size,
                              hipStream_t stream) {
    const float* q      = (const float*)d_in[0];
    const float* v      = (const float*)d_in[1];
    const float* w_q    = (const float*)d_in[2];
    const float* b_q    = (const float*)d_in[3];
    const float* w_kc   = (const float*)d_in[4];
    const float* b_kc   = (const float*)d_in[5];
    const float* w_kd   = (const float*)d_in[6];
    const float* b_kd   = (const float*)d_in[7];
    const float* w_v    = (const float*)d_in[8];
    const float* b_v    = (const float*)d_in[9];
    const float* temp_c = (const float*)d_in[10];
    const float* temp_d = (const float*)d_in[11];
    const float* bn_g   = (const float*)d_in[12];
    const float* bn_b   = (const float*)d_in[13];
    const float* bn_m   = (const float*)d_in[14];
    const float* bn_v   = (const float*)d_in[15];
    float* out = (float*)d_out;

    float* ws   = (float*)d_ws;
    float* qv   = ws;                     // B*DO        = 16384
    float* wqkc = qv   + B*DO;            // B*NH*DO     = 131072
    float* wqkd = wqkc + B*NH*DO;         // 131072
    float* qbc  = wqkd + B*NH*DO;         // 512
    float* qbd  = qbc  + B*NH;            // 512
    float* gate = qbd  + B*NH;            // B*NH*HW     = 524288
    float* ebuf = gate + B*NH*HW;         // 524288
    float* mz   = ebuf + B*NH*HW;         // B*NCH*NH*2  = 16384
    float* pvp  = mz   + B*NCH*NH*2;      // B*4*NH*DO   = 524288
    float* attn = pvp  + B*4*NH*DO;       // B*DO        = 16384

    k1_qv <<<dim3(16, B),    256, 0, stream>>>(q, w_q, b_q, qv);
    k2_wqk<<<B*NH,           256, 0, stream>>>(qv, w_kc, b_kc, w_kd, b_kd, temp_c, temp_d,
                                               wqkc, wqkd, qbc, qbd);
    k3    <<<dim3(NCH, B),   512, 0, stream>>>(v, wqkc, wqkd, qbc, qbd, gate, ebuf, mz);
    kPp   <<<dim3(8, 4, B),  256, 0, stream>>>(v, ebuf, mz, pvp);
    k4c   <<<B,              256, 0, stream>>>(pvp, w_v, b_v, attn);
    k5_out<<<dim3(DO, B),    256, 0, stream>>>(v, gate, attn, bn_g, bn_b, bn_m, bn_v, out);
}

// Round 7
// 100.892 us; speedup vs baseline: 1.1365x; 1.1365x over previous
//
#include <hip/hip_runtime.h>
#include <math.h>

#define B    64
#define DQ   512
#define DO   256
#define NH   8
#define DH   32
#define HW   1024
#define NCH  16     // s-chunks per image
#define CHS  64     // s per chunk

// ---------------------------------------------------------------- k1: qv = q @ w_q.T + b_q   (wave-per-output GEMV)
__global__ __launch_bounds__(256) void k1_qv(const float* __restrict__ q,
                                             const float* __restrict__ w_q,
                                             const float* __restrict__ b_q,
                                             float* __restrict__ qv) {
    int cg = blockIdx.x, b = blockIdx.y;
    int t = threadIdx.x;
    int wid = t >> 6, lane = t & 63;
    const float4* qrow = reinterpret_cast<const float4*>(q + (size_t)b*DQ);
    float4 q0 = qrow[lane*2], q1 = qrow[lane*2 + 1];
    #pragma unroll
    for (int r = 0; r < 4; ++r) {
        int c = cg*16 + wid*4 + r;
        const float4* wrow = reinterpret_cast<const float4*>(w_q + (size_t)c*DQ);
        float4 w0 = wrow[lane*2], w1 = wrow[lane*2 + 1];
        float acc = q0.x*w0.x + q0.y*w0.y + q0.z*w0.z + q0.w*w0.w
                  + q1.x*w1.x + q1.y*w1.y + q1.z*w1.z + q1.w*w1.w;
        #pragma unroll
        for (int k = 32; k > 0; k >>= 1) acc += __shfl_xor(acc, k);
        if (lane == 0) qv[b*DO + c] = acc + b_q[c];
    }
}

// ---------------------------------------------------------------- k2: fold qv into kc/kd weights
__global__ void k2_wqk(const float* __restrict__ qv,
                       const float* __restrict__ w_kc, const float* __restrict__ b_kc,
                       const float* __restrict__ w_kd, const float* __restrict__ b_kd,
                       const float* __restrict__ temp_c, const float* __restrict__ temp_d,
                       float* __restrict__ wqkc, float* __restrict__ wqkd,
                       float* __restrict__ qbc, float* __restrict__ qbd) {
    int bn = blockIdx.x;              // b*8 + n
    int n  = bn & 7;
    int t  = threadIdx.x;             // c
    __shared__ float qvs[DH];
    if (t < DH) qvs[t] = qv[(bn >> 3)*DO + n*DH + t];
    __syncthreads();
    float itc = 1.0f / temp_c[0];
    float itd = 1.0f / temp_d[0];
    float ac = 0.f, ad = 0.f;
    #pragma unroll
    for (int d = 0; d < DH; ++d) {
        float qd = qvs[d];
        ac += qd * w_kc[(n*DH + d)*DO + t];
        ad += qd * w_kd[(n*DH + d)*DO + t];
    }
    wqkc[bn*DO + t] = ac * itc;
    wqkd[bn*DO + t] = ad * itd;
    if (t == 0) {
        float sc = 0.f;
        for (int d = 0; d < DH; ++d) sc += qvs[d]*b_kc[n*DH + d];
        qbc[bn] = sc * itc;
    }
    if (t == 1) {
        float sd = 0.f;
        for (int d = 0; d < DH; ++d) sd += qvs[d]*b_kd[n*DH + d];
        qbd[bn] = sd * itd;
    }
}

// ---------------------------------------------------------------- k3f: logits + gate + local softmax + FUSED partial pool
// grid (NCH, B), block 512 (8 waves).
__global__ __launch_bounds__(512, 8)
void k3f(const float* __restrict__ v,
         const float* __restrict__ wqkc, const float* __restrict__ wqkd,
         const float* __restrict__ qbc,  const float* __restrict__ qbd,
         float* __restrict__ gate, float* __restrict__ pvp, float* __restrict__ mz) {
    __shared__ float pc[8*NH*CHS];   // 16 KB
    __shared__ float pd[8*NH*CHS];   // 16 KB
    __shared__ float e_lds[NH][CHS]; // 2 KB
    int ch = blockIdx.x, b = blockIdx.y;
    int t  = threadIdx.x;
    int s0 = ch*CHS;
    int bn0 = b*NH;
    int sl = t & 63;
    int csub = __builtin_amdgcn_readfirstlane(t >> 6);

    // ---- phase 1: partial logits, wave csub owns 32 channels, lanes over s (coalesced)
    {
        const float* vb = v + (size_t)b*DO*HW + s0 + sl;
        const float* wc = wqkc + bn0*DO;
        const float* wd = wqkd + bn0*DO;
        float ac[NH] = {0,0,0,0,0,0,0,0};
        float ad[NH] = {0,0,0,0,0,0,0,0};
        int cbase = csub*32;
        for (int c0 = cbase; c0 < cbase + 32; c0 += 4) {
            float v0 = vb[(size_t)(c0+0)*HW];
            float v1 = vb[(size_t)(c0+1)*HW];
            float v2 = vb[(size_t)(c0+2)*HW];
            float v3 = vb[(size_t)(c0+3)*HW];
            #pragma unroll
            for (int n = 0; n < NH; ++n) {
                ac[n] += v0*wc[n*DO+c0] + v1*wc[n*DO+c0+1] + v2*wc[n*DO+c0+2] + v3*wc[n*DO+c0+3];
                ad[n] += v0*wd[n*DO+c0] + v1*wd[n*DO+c0+1] + v2*wd[n*DO+c0+2] + v3*wd[n*DO+c0+3];
            }
        }
        #pragma unroll
        for (int n = 0; n < NH; ++n) {
            pc[(csub*NH + n)*CHS + sl] = ac[n];
            pd[(csub*NH + n)*CHS + sl] = ad[n];
        }
    }
    __syncthreads();

    // ---- phase 2: reduce csubs; wave n owns head n; gate + e_lds + (m,z)
    {
        int n = csub, s = sl;
        float lc = qbc[bn0+n], ld = qbd[bn0+n];
        #pragma unroll
        for (int k = 0; k < 8; ++k) {
            lc += pc[(k*NH + n)*CHS + s];
            ld += pd[(k*NH + n)*CHS + s];
        }
        gate[(bn0+n)*HW + s0 + s] = 1.0f/(1.0f + __expf(-ld));
        float m = lc;
        #pragma unroll
        for (int k = 32; k > 0; k >>= 1) m = fmaxf(m, __shfl_xor(m, k));
        float e = __expf(lc - m);
        e_lds[n][s] = e;
        float z = e;
        #pragma unroll
        for (int k = 32; k > 0; k >>= 1) z += __shfl_xor(z, k);
        if (s == 0) {
            float* mzp = mz + ((size_t)(b*NCH + ch)*NH + n)*2;
            mzp[0] = m; mzp[1] = z;
        }
    }
    __syncthreads();

    // ---- phase 3: partial pool, transposed mapping: thread -> (c, 4 heads), s serial.
    // v re-read is this block's own tile (L1/L2-hot). Zero shuffles, e_lds reads broadcast.
    {
        int ng = t >> 8;                 // 0 or 1
        int c  = t & 255;
        const float* vrow = v + ((size_t)(b*DO + c))*HW + s0;
        float a0 = 0.f, a1 = 0.f, a2 = 0.f, a3 = 0.f;
        #pragma unroll
        for (int s4 = 0; s4 < 16; ++s4) {
            float4 v4 = *reinterpret_cast<const float4*>(vrow + s4*4);
            float4 e0 = *reinterpret_cast<const float4*>(&e_lds[ng*4+0][s4*4]);
            float4 e1 = *reinterpret_cast<const float4*>(&e_lds[ng*4+1][s4*4]);
            float4 e2 = *reinterpret_cast<const float4*>(&e_lds[ng*4+2][s4*4]);
            float4 e3 = *reinterpret_cast<const float4*>(&e_lds[ng*4+3][s4*4]);
            a0 += v4.x*e0.x + v4.y*e0.y + v4.z*e0.z + v4.w*e0.w;
            a1 += v4.x*e1.x + v4.y*e1.y + v4.z*e1.z + v4.w*e1.w;
            a2 += v4.x*e2.x + v4.y*e2.y + v4.z*e2.z + v4.w*e2.w;
            a3 += v4.x*e3.x + v4.y*e3.y + v4.z*e3.z + v4.w*e3.w;
        }
        size_t pb = ((size_t)(b*NCH + ch)*NH + ng*4)*DO + c;
        pvp[pb]        = a0;
        pvp[pb + DO]   = a1;
        pvp[pb + 2*DO] = a2;
        pvp[pb + 3*DO] = a3;
    }
}

// ---------------------------------------------------------------- k4c: softmax-scale combine of 16 chunks + GEMV
__global__ void k4c(const float* __restrict__ pvp, const float* __restrict__ mz,
                    const float* __restrict__ w_v, const float* __restrict__ b_v,
                    float* __restrict__ attn) {
    __shared__ float scale[NCH][NH];
    __shared__ float pv_lds[NH*DO];
    int b = blockIdx.x, t = threadIdx.x;
    if (t < NH) {
        int n = t;
        float M = -1e30f;
        for (int ch = 0; ch < NCH; ++ch)
            M = fmaxf(M, mz[((size_t)(b*NCH+ch)*NH+n)*2]);
        float Z = 0.f;
        for (int ch = 0; ch < NCH; ++ch) {
            float sc = __expf(mz[((size_t)(b*NCH+ch)*NH+n)*2] - M);
            Z += sc * mz[((size_t)(b*NCH+ch)*NH+n)*2 + 1];
            scale[ch][n] = sc;
        }
        float inv = 1.0f/Z;
        for (int ch = 0; ch < NCH; ++ch) scale[ch][n] *= inv;
    }
    __syncthreads();
    for (int i = t; i < NH*DO; i += 256) {
        int n = i >> 8;
        float s = 0.f;
        #pragma unroll 4
        for (int ch = 0; ch < NCH; ++ch)
            s += scale[ch][n] * pvp[(size_t)(b*NCH + ch)*NH*DO + i];
        pv_lds[i] = s;
    }
    __syncthreads();
    int n = t >> 5;
    float acc = b_v[t];
    const float4* w4 = reinterpret_cast<const float4*>(w_v + t*DO);
    #pragma unroll 4
    for (int c4 = 0; c4 < DO/4; ++c4) {
        float4 wv = w4[c4];
        int c = c4*4;
        acc += pv_lds[n*DO+c]*wv.x + pv_lds[n*DO+c+1]*wv.y + pv_lds[n*DO+c+2]*wv.z + pv_lds[n*DO+c+3]*wv.w;
    }
    attn[b*DO + t] = acc;
}

// ---------------------------------------------------------------- k5: out = leaky(bn(gate[s^T]*attn + v))
__global__ void k5_out(const float* __restrict__ v, const float* __restrict__ gate,
                       const float* __restrict__ attn,
                       const float* __restrict__ bn_g, const float* __restrict__ bn_b,
                       const float* __restrict__ bn_m, const float* __restrict__ bn_v,
                       float* __restrict__ out) {
    int c = blockIdx.x, b = blockIdx.y;
    int n = c >> 5, d = c & 31;
    int t = threadIdx.x;
    __shared__ float g[32*33];             // stride 33 kills transpose bank conflicts
    float4 gv = reinterpret_cast<const float4*>(gate + (b*NH + n)*HW)[t];
    int s0 = t*4;
    int ga = s0 >> 5, gb = s0 & 31;
    g[ga*33 + gb + 0] = gv.x;
    g[ga*33 + gb + 1] = gv.y;
    g[ga*33 + gb + 2] = gv.z;
    g[ga*33 + gb + 3] = gv.w;
    __syncthreads();
    float av   = attn[(b*NH + n)*DH + d];
    float inv  = bn_g[c] / sqrtf(bn_v[c] + 1e-5f);
    float mean = bn_m[c], beta = bn_b[c];
    size_t base = ((size_t)(b*DO + c))*HW;
    float4 r4 = reinterpret_cast<const float4*>(v + base)[t];
    int l = 4*t;
    int i_ = l >> 5, j_ = l & 31;          // gate index s = j*32 + i
    float x0 = g[(j_+0)*33 + i_]*av + r4.x;
    float x1 = g[(j_+1)*33 + i_]*av + r4.y;
    float x2 = g[(j_+2)*33 + i_]*av + r4.z;
    float x3 = g[(j_+3)*33 + i_]*av + r4.w;
    float y0 = (x0 - mean)*inv + beta; y0 = y0 >= 0.f ? y0 : 0.1f*y0;
    float y1 = (x1 - mean)*inv + beta; y1 = y1 >= 0.f ? y1 : 0.1f*y1;
    float y2 = (x2 - mean)*inv + beta; y2 = y2 >= 0.f ? y2 : 0.1f*y2;
    float y3 = (x3 - mean)*inv + beta; y3 = y3 >= 0.f ? y3 : 0.1f*y3;
    reinterpret_cast<float4*>(out + base)[t] = make_float4(y0, y1, y2, y3);
}

// ----------------------------------------------------------------
extern "C" void kernel_launch(void* const* d_in, const int* in_sizes, int n_in,
                              void* d_out, int out_size, void* d_ws, size_t ws_size,
                              hipStream_t stream) {
    const float* q      = (const float*)d_in[0];
    const float* v      = (const float*)d_in[1];
    const float* w_q    = (const float*)d_in[2];
    const float* b_q    = (const float*)d_in[3];
    const float* w_kc   = (const float*)d_in[4];
    const float* b_kc   = (const float*)d_in[5];
    const float* w_kd   = (const float*)d_in[6];
    const float* b_kd   = (const float*)d_in[7];
    const float* w_v    = (const float*)d_in[8];
    const float* b_v    = (const float*)d_in[9];
    const float* temp_c = (const float*)d_in[10];
    const float* temp_d = (const float*)d_in[11];
    const float* bn_g   = (const float*)d_in[12];
    const float* bn_b   = (const float*)d_in[13];
    const float* bn_m   = (const float*)d_in[14];
    const float* bn_v   = (const float*)d_in[15];
    float* out = (float*)d_out;

    float* ws   = (float*)d_ws;
    float* qv   = ws;                     // B*DO         = 16384
    float* wqkc = qv   + B*DO;            // B*NH*DO      = 131072
    float* wqkd = wqkc + B*NH*DO;         // 131072
    float* qbc  = wqkd + B*NH*DO;         // 512
    float* qbd  = qbc  + B*NH;            // 512
    float* gate = qbd  + B*NH;            // B*NH*HW      = 524288
    float* mz   = gate + B*NH*HW;         // B*NCH*NH*2   = 16384
    float* pvp  = mz   + B*NCH*NH*2;      // B*NCH*NH*DO  = 2097152
    float* attn = pvp  + B*NCH*NH*DO;     // B*DO         = 16384

    k1_qv <<<dim3(16, B),    256, 0, stream>>>(q, w_q, b_q, qv);
    k2_wqk<<<B*NH,           256, 0, stream>>>(qv, w_kc, b_kc, w_kd, b_kd, temp_c, temp_d,
                                               wqkc, wqkd, qbc, qbd);
    k3f   <<<dim3(NCH, B),   512, 0, stream>>>(v, wqkc, wqkd, qbc, qbd, gate, pvp, mz);
    k4c   <<<B,              256, 0, stream>>>(pvp, mz, w_v, b_v, attn);
    k5_out<<<dim3(DO, B),    256, 0, stream>>>(v, gate, attn, bn_g, bn_b, bn_m, bn_v, out);
}

// Round 8
// 98.887 us; speedup vs baseline: 1.1595x; 1.0203x over previous
//
#include <hip/hip_runtime.h>
#include <math.h>

#define B    64
#define DQ   512
#define DO   256
#define NH   8
#define DH   32
#define HW   1024
#define NCH  16     // s-chunks per image
#define CHS  64     // s per chunk

// ---------------------------------------------------------------- k1: qv = q @ w_q.T + b_q   (wave-per-output GEMV)
__global__ __launch_bounds__(256) void k1_qv(const float* __restrict__ q,
                                             const float* __restrict__ w_q,
                                             const float* __restrict__ b_q,
                                             float* __restrict__ qv) {
    int cg = blockIdx.x, b = blockIdx.y;
    int t = threadIdx.x;
    int wid = t >> 6, lane = t & 63;
    const float4* qrow = reinterpret_cast<const float4*>(q + (size_t)b*DQ);
    float4 q0 = qrow[lane*2], q1 = qrow[lane*2 + 1];
    #pragma unroll
    for (int r = 0; r < 4; ++r) {
        int c = cg*16 + wid*4 + r;
        const float4* wrow = reinterpret_cast<const float4*>(w_q + (size_t)c*DQ);
        float4 w0 = wrow[lane*2], w1 = wrow[lane*2 + 1];
        float acc = q0.x*w0.x + q0.y*w0.y + q0.z*w0.z + q0.w*w0.w
                  + q1.x*w1.x + q1.y*w1.y + q1.z*w1.z + q1.w*w1.w;
        #pragma unroll
        for (int k = 32; k > 0; k >>= 1) acc += __shfl_xor(acc, k);
        if (lane == 0) qv[b*DO + c] = acc + b_q[c];
    }
}

// ---------------------------------------------------------------- k2: fold qv into kc/kd weights
__global__ void k2_wqk(const float* __restrict__ qv,
                       const float* __restrict__ w_kc, const float* __restrict__ b_kc,
                       const float* __restrict__ w_kd, const float* __restrict__ b_kd,
                       const float* __restrict__ temp_c, const float* __restrict__ temp_d,
                       float* __restrict__ wqkc, float* __restrict__ wqkd,
                       float* __restrict__ qbc, float* __restrict__ qbd) {
    int bn = blockIdx.x;              // b*8 + n
    int n  = bn & 7;
    int t  = threadIdx.x;             // c
    __shared__ float qvs[DH];
    if (t < DH) qvs[t] = qv[(bn >> 3)*DO + n*DH + t];
    __syncthreads();
    float itc = 1.0f / temp_c[0];
    float itd = 1.0f / temp_d[0];
    float ac = 0.f, ad = 0.f;
    #pragma unroll
    for (int d = 0; d < DH; ++d) {
        float qd = qvs[d];
        ac += qd * w_kc[(n*DH + d)*DO + t];
        ad += qd * w_kd[(n*DH + d)*DO + t];
    }
    wqkc[bn*DO + t] = ac * itc;
    wqkd[bn*DO + t] = ad * itd;
    if (t == 0) {
        float sc = 0.f;
        for (int d = 0; d < DH; ++d) sc += qvs[d]*b_kc[n*DH + d];
        qbc[bn] = sc * itc;
    }
    if (t == 1) {
        float sd = 0.f;
        for (int d = 0; d < DH; ++d) sd += qvs[d]*b_kd[n*DH + d];
        qbd[bn] = sd * itd;
    }
}

// ---------------------------------------------------------------- k3f: logits + gate + local softmax + fused partial pool
// grid (NCH, B), block 512 (8 waves). Software-pipelined loads for latency hiding.
__global__ __launch_bounds__(512, 8)
void k3f(const float* __restrict__ v,
         const float* __restrict__ wqkc, const float* __restrict__ wqkd,
         const float* __restrict__ qbc,  const float* __restrict__ qbd,
         float* __restrict__ gate, float* __restrict__ pvp, float* __restrict__ mz) {
    __shared__ float pc[8*NH*CHS];   // 16 KB
    __shared__ float pd[8*NH*CHS];   // 16 KB
    __shared__ float e_lds[NH][CHS]; // 2 KB
    int ch = blockIdx.x, b = blockIdx.y;
    int t  = threadIdx.x;
    int s0 = ch*CHS;
    int bn0 = b*NH;
    int sl = t & 63;
    int csub = __builtin_amdgcn_readfirstlane(t >> 6);

    // ---- phase 1: partial logits; wave csub owns 32 channels, lanes over s (coalesced).
    // 8-value register batches, loaded one batch ahead: ~1 full HBM latency exposed, not 8.
    {
        const float* vb = v + (size_t)b*DO*HW + s0 + sl;
        const float* wc = wqkc + bn0*DO;
        const float* wd = wqkd + bn0*DO;
        float ac[NH] = {0,0,0,0,0,0,0,0};
        float ad[NH] = {0,0,0,0,0,0,0,0};
        int cbase = csub*32;
        float cur[8], nxt[8];
        #pragma unroll
        for (int j = 0; j < 8; ++j) cur[j] = vb[(size_t)(cbase+j)*HW];
        #pragma unroll
        for (int g = 0; g < 4; ++g) {
            int c0 = cbase + g*8;
            if (g < 3) {
                #pragma unroll
                for (int j = 0; j < 8; ++j) nxt[j] = vb[(size_t)(c0+8+j)*HW];
            }
            #pragma unroll
            for (int j = 0; j < 8; ++j) {
                float vv = cur[j];
                #pragma unroll
                for (int n = 0; n < NH; ++n) {
                    ac[n] = fmaf(vv, wc[n*DO+c0+j], ac[n]);
                    ad[n] = fmaf(vv, wd[n*DO+c0+j], ad[n]);
                }
            }
            #pragma unroll
            for (int j = 0; j < 8; ++j) cur[j] = nxt[j];
        }
        #pragma unroll
        for (int n = 0; n < NH; ++n) {
            pc[(csub*NH + n)*CHS + sl] = ac[n];
            pd[(csub*NH + n)*CHS + sl] = ad[n];
        }
    }
    __syncthreads();

    // ---- phase 2: reduce csubs; wave n owns head n; gate + e_lds + (m,z)
    {
        int n = csub, s = sl;
        float lc = qbc[bn0+n], ld = qbd[bn0+n];
        #pragma unroll
        for (int k = 0; k < 8; ++k) {
            lc += pc[(k*NH + n)*CHS + s];
            ld += pd[(k*NH + n)*CHS + s];
        }
        gate[(bn0+n)*HW + s0 + s] = 1.0f/(1.0f + __expf(-ld));
        float m = lc;
        #pragma unroll
        for (int k = 32; k > 0; k >>= 1) m = fmaxf(m, __shfl_xor(m, k));
        float e = __expf(lc - m);
        e_lds[n][s] = e;
        float z = e;
        #pragma unroll
        for (int k = 32; k > 0; k >>= 1) z += __shfl_xor(z, k);
        if (s == 0) {
            float* mzp = mz + ((size_t)(b*NCH + ch)*NH + n)*2;
            mzp[0] = m; mzp[1] = z;
        }
    }
    __syncthreads();

    // ---- phase 3: partial pool, transposed mapping: thread -> (c, 4 heads), s serial.
    // L2-hot tile re-read, pipelined one 4xfloat4 batch ahead.
    {
        int ng = t >> 8;                 // 0 or 1
        int c  = t & 255;
        const float* vrow = v + ((size_t)(b*DO + c))*HW + s0;
        float a0 = 0.f, a1 = 0.f, a2 = 0.f, a3 = 0.f;
        float4 vv[4], vnx[4];
        #pragma unroll
        for (int j = 0; j < 4; ++j) vv[j] = *reinterpret_cast<const float4*>(vrow + j*4);
        #pragma unroll
        for (int g = 0; g < 4; ++g) {
            if (g < 3) {
                #pragma unroll
                for (int j = 0; j < 4; ++j)
                    vnx[j] = *reinterpret_cast<const float4*>(vrow + (g+1)*16 + j*4);
            }
            #pragma unroll
            for (int j = 0; j < 4; ++j) {
                int sb = g*16 + j*4;
                float4 v4 = vv[j];
                float4 e0 = *reinterpret_cast<const float4*>(&e_lds[ng*4+0][sb]);
                float4 e1 = *reinterpret_cast<const float4*>(&e_lds[ng*4+1][sb]);
                float4 e2 = *reinterpret_cast<const float4*>(&e_lds[ng*4+2][sb]);
                float4 e3 = *reinterpret_cast<const float4*>(&e_lds[ng*4+3][sb]);
                a0 += v4.x*e0.x + v4.y*e0.y + v4.z*e0.z + v4.w*e0.w;
                a1 += v4.x*e1.x + v4.y*e1.y + v4.z*e1.z + v4.w*e1.w;
                a2 += v4.x*e2.x + v4.y*e2.y + v4.z*e2.z + v4.w*e2.w;
                a3 += v4.x*e3.x + v4.y*e3.y + v4.z*e3.z + v4.w*e3.w;
            }
            #pragma unroll
            for (int j = 0; j < 4; ++j) vv[j] = vnx[j];
        }
        size_t pb = ((size_t)(b*NCH + ch)*NH + ng*4)*DO + c;
        pvp[pb]        = a0;
        pvp[pb + DO]   = a1;
        pvp[pb + 2*DO] = a2;
        pvp[pb + 3*DO] = a3;
    }
}

// ---------------------------------------------------------------- k4c: softmax-scale combine of 16 chunks + GEMV
__global__ void k4c(const float* __restrict__ pvp, const float* __restrict__ mz,
                    const float* __restrict__ w_v, const float* __restrict__ b_v,
                    float* __restrict__ attn) {
    __shared__ float scale[NCH][NH];
    __shared__ float pv_lds[NH*DO];
    int b = blockIdx.x, t = threadIdx.x;
    if (t < NH) {
        int n = t;
        float M = -1e30f;
        for (int ch = 0; ch < NCH; ++ch)
            M = fmaxf(M, mz[((size_t)(b*NCH+ch)*NH+n)*2]);
        float Z = 0.f;
        for (int ch = 0; ch < NCH; ++ch) {
            float sc = __expf(mz[((size_t)(b*NCH+ch)*NH+n)*2] - M);
            Z += sc * mz[((size_t)(b*NCH+ch)*NH+n)*2 + 1];
            scale[ch][n] = sc;
        }
        float inv = 1.0f/Z;
        for (int ch = 0; ch < NCH; ++ch) scale[ch][n] *= inv;
    }
    __syncthreads();
    for (int i = t; i < NH*DO; i += 256) {
        int n = i >> 8;
        float s = 0.f;
        #pragma unroll 4
        for (int ch = 0; ch < NCH; ++ch)
            s += scale[ch][n] * pvp[(size_t)(b*NCH + ch)*NH*DO + i];
        pv_lds[i] = s;
    }
    __syncthreads();
    int n = t >> 5;
    float acc = b_v[t];
    const float4* w4 = reinterpret_cast<const float4*>(w_v + t*DO);
    #pragma unroll 4
    for (int c4 = 0; c4 < DO/4; ++c4) {
        float4 wv = w4[c4];
        int c = c4*4;
        acc += pv_lds[n*DO+c]*wv.x + pv_lds[n*DO+c+1]*wv.y + pv_lds[n*DO+c+2]*wv.z + pv_lds[n*DO+c+3]*wv.w;
    }
    attn[b*DO + t] = acc;
}

// ---------------------------------------------------------------- k5: out = leaky(bn(gate[s^T]*attn + v))
__global__ void k5_out(const float* __restrict__ v, const float* __restrict__ gate,
                       const float* __restrict__ attn,
                       const float* __restrict__ bn_g, const float* __restrict__ bn_b,
                       const float* __restrict__ bn_m, const float* __restrict__ bn_v,
                       float* __restrict__ out) {
    int c = blockIdx.x, b = blockIdx.y;
    int n = c >> 5, d = c & 31;
    int t = threadIdx.x;
    __shared__ float g[32*33];             // stride 33 kills transpose bank conflicts
    float4 gv = reinterpret_cast<const float4*>(gate + (b*NH + n)*HW)[t];
    int s0 = t*4;
    int ga = s0 >> 5, gb = s0 & 31;
    g[ga*33 + gb + 0] = gv.x;
    g[ga*33 + gb + 1] = gv.y;
    g[ga*33 + gb + 2] = gv.z;
    g[ga*33 + gb + 3] = gv.w;
    __syncthreads();
    float av   = attn[(b*NH + n)*DH + d];
    float inv  = bn_g[c] / sqrtf(bn_v[c] + 1e-5f);
    float mean = bn_m[c], beta = bn_b[c];
    size_t base = ((size_t)(b*DO + c))*HW;
    float4 r4 = reinterpret_cast<const float4*>(v + base)[t];
    int l = 4*t;
    int i_ = l >> 5, j_ = l & 31;          // gate index s = j*32 + i
    float x0 = g[(j_+0)*33 + i_]*av + r4.x;
    float x1 = g[(j_+1)*33 + i_]*av + r4.y;
    float x2 = g[(j_+2)*33 + i_]*av + r4.z;
    float x3 = g[(j_+3)*33 + i_]*av + r4.w;
    float y0 = (x0 - mean)*inv + beta; y0 = y0 >= 0.f ? y0 : 0.1f*y0;
    float y1 = (x1 - mean)*inv + beta; y1 = y1 >= 0.f ? y1 : 0.1f*y1;
    float y2 = (x2 - mean)*inv + beta; y2 = y2 >= 0.f ? y2 : 0.1f*y2;
    float y3 = (x3 - mean)*inv + beta; y3 = y3 >= 0.f ? y3 : 0.1f*y3;
    reinterpret_cast<float4*>(out + base)[t] = make_float4(y0, y1, y2, y3);
}

// ----------------------------------------------------------------
extern "C" void kernel_launch(void* const* d_in, const int* in_sizes, int n_in,
                              void* d_out, int out_size, void* d_ws, size_t ws_size,
                              hipStream_t stream) {
    const float* q      = (const float*)d_in[0];
    const float* v      = (const float*)d_in[1];
    const float* w_q    = (const float*)d_in[2];
    const float* b_q    = (const float*)d_in[3];
    const float* w_kc   = (const float*)d_in[4];
    const float* b_kc   = (const float*)d_in[5];
    const float* w_kd   = (const float*)d_in[6];
    const float* b_kd   = (const float*)d_in[7];
    const float* w_v    = (const float*)d_in[8];
    const float* b_v    = (const float*)d_in[9];
    const float* temp_c = (const float*)d_in[10];
    const float* temp_d = (const float*)d_in[11];
    const float* bn_g   = (const float*)d_in[12];
    const float* bn_b   = (const float*)d_in[13];
    const float* bn_m   = (const float*)d_in[14];
    const float* bn_v   = (const float*)d_in[15];
    float* out = (float*)d_out;

    float* ws   = (float*)d_ws;
    float* qv   = ws;                     // B*DO         = 16384
    float* wqkc = qv   + B*DO;            // B*NH*DO      = 131072
    float* wqkd = wqkc + B*NH*DO;         // 131072
    float* qbc  = wqkd + B*NH*DO;         // 512
    float* qbd  = qbc  + B*NH;            // 512
    float* gate = qbd  + B*NH;            // B*NH*HW      = 524288
    float* mz   = gate + B*NH*HW;         // B*NCH*NH*2   = 16384
    float* pvp  = mz   + B*NCH*NH*2;      // B*NCH*NH*DO  = 2097152
    float* attn = pvp  + B*NCH*NH*DO;     // B*DO         = 16384

    k1_qv <<<dim3(16, B),    256, 0, stream>>>(q, w_q, b_q, qv);
    k2_wqk<<<B*NH,           256, 0, stream>>>(qv, w_kc, b_kc, w_kd, b_kd, temp_c, temp_d,
                                               wqkc, wqkd, qbc, qbd);
    k3f   <<<dim3(NCH, B),   512, 0, stream>>>(v, wqkc, wqkd, qbc, qbd, gate, pvp, mz);
    k4c   <<<B,              256, 0, stream>>>(pvp, mz, w_v, b_v, attn);
    k5_out<<<dim3(DO, B),    256, 0, stream>>>(v, gate, attn, bn_g, bn_b, bn_m, bn_v, out);
}

// Round 9
// 82.909 us; speedup vs baseline: 1.3830x; 1.1927x over previous
//
#include <hip/hip_runtime.h>
#include <math.h>

#define B    64
#define DQ   512
#define DO   256
#define NH   8
#define DH   32
#define HW   1024
#define NCH  4      // s-chunks per image
#define CHS  256    // s per chunk

// ---------------------------------------------------------------- k1: qv = q @ w_q.T + b_q   (wave-per-output GEMV)
__global__ __launch_bounds__(256) void k1_qv(const float* __restrict__ q,
                                             const float* __restrict__ w_q,
                                             const float* __restrict__ b_q,
                                             float* __restrict__ qv) {
    int cg = blockIdx.x, b = blockIdx.y;
    int t = threadIdx.x;
    int wid = t >> 6, lane = t & 63;
    const float4* qrow = reinterpret_cast<const float4*>(q + (size_t)b*DQ);
    float4 q0 = qrow[lane*2], q1 = qrow[lane*2 + 1];
    #pragma unroll
    for (int r = 0; r < 4; ++r) {
        int c = cg*16 + wid*4 + r;
        const float4* wrow = reinterpret_cast<const float4*>(w_q + (size_t)c*DQ);
        float4 w0 = wrow[lane*2], w1 = wrow[lane*2 + 1];
        float acc = q0.x*w0.x + q0.y*w0.y + q0.z*w0.z + q0.w*w0.w
                  + q1.x*w1.x + q1.y*w1.y + q1.z*w1.z + q1.w*w1.w;
        #pragma unroll
        for (int k = 32; k > 0; k >>= 1) acc += __shfl_xor(acc, k);
        if (lane == 0) qv[b*DO + c] = acc + b_q[c];
    }
}

// ---------------------------------------------------------------- k2: fold qv into kc/kd weights
__global__ void k2_wqk(const float* __restrict__ qv,
                       const float* __restrict__ w_kc, const float* __restrict__ b_kc,
                       const float* __restrict__ w_kd, const float* __restrict__ b_kd,
                       const float* __restrict__ temp_c, const float* __restrict__ temp_d,
                       float* __restrict__ wqkc, float* __restrict__ wqkd,
                       float* __restrict__ qbc, float* __restrict__ qbd) {
    int bn = blockIdx.x;              // b*8 + n
    int n  = bn & 7;
    int t  = threadIdx.x;             // c
    __shared__ float qvs[DH];
    if (t < DH) qvs[t] = qv[(bn >> 3)*DO + n*DH + t];
    __syncthreads();
    float itc = 1.0f / temp_c[0];
    float itd = 1.0f / temp_d[0];
    float ac = 0.f, ad = 0.f;
    #pragma unroll
    for (int d = 0; d < DH; ++d) {
        float qd = qvs[d];
        ac += qd * w_kc[(n*DH + d)*DO + t];
        ad += qd * w_kd[(n*DH + d)*DO + t];
    }
    wqkc[bn*DO + t] = ac * itc;
    wqkd[bn*DO + t] = ad * itd;
    if (t == 0) {
        float sc = 0.f;
        for (int d = 0; d < DH; ++d) sc += qvs[d]*b_kc[n*DH + d];
        qbc[bn] = sc * itc;
    }
    if (t == 1) {
        float sd = 0.f;
        for (int d = 0; d < DH; ++d) sd += qvs[d]*b_kd[n*DH + d];
        qbd[bn] = sd * itd;
    }
}

// ---------------------------------------------------------------- k3g: logits + gate + wave-local softmax + partial pool
// grid (NCH=4, B) = 256 blocks (1/CU), block 512 (8 waves).
// Phase 1: wave n owns head n; lanes hold 4 s each (float4 loads, 1KB/instr).
__global__ __launch_bounds__(512)
void k3g(const float* __restrict__ v,
         const float* __restrict__ wqkc, const float* __restrict__ wqkd,
         const float* __restrict__ qbc,  const float* __restrict__ qbd,
         float* __restrict__ gate, float* __restrict__ pvp, float* __restrict__ mz) {
    __shared__ float e_lds[NH][CHS];     // 8 KB
    int ch = blockIdx.x, b = blockIdx.y;
    int t  = threadIdx.x;
    int s0 = ch*CHS;
    int bn0 = b*NH;
    int lane = t & 63;
    int w = __builtin_amdgcn_readfirstlane(t >> 6);   // wave id = head, wave-uniform

    // ---- phase 1: head-w logits for 4 s-positions per lane; weights via scalar loads
    float ac0=0.f, ac1=0.f, ac2=0.f, ac3=0.f;
    float ad0=0.f, ad1=0.f, ad2=0.f, ad3=0.f;
    {
        const float* vb = v + (size_t)b*DO*HW + s0 + lane*4;
        const float* wc = wqkc + (size_t)(bn0 + w)*DO;
        const float* wd = wqkd + (size_t)(bn0 + w)*DO;
        #pragma unroll 8
        for (int c = 0; c < DO; ++c) {
            float4 v4 = *reinterpret_cast<const float4*>(vb + (size_t)c*HW);
            float wcv = wc[c];
            float wdv = wd[c];
            ac0 = fmaf(wcv, v4.x, ac0); ac1 = fmaf(wcv, v4.y, ac1);
            ac2 = fmaf(wcv, v4.z, ac2); ac3 = fmaf(wcv, v4.w, ac3);
            ad0 = fmaf(wdv, v4.x, ad0); ad1 = fmaf(wdv, v4.y, ad1);
            ad2 = fmaf(wdv, v4.z, ad2); ad3 = fmaf(wdv, v4.w, ad3);
        }
    }

    // ---- phase 2: wave-local gate + softmax (head w fully inside wave w; no barrier needed yet)
    {
        float qc = qbc[bn0 + w], qd = qbd[bn0 + w];
        float g0 = 1.0f/(1.0f + __expf(-(ad0 + qd)));
        float g1 = 1.0f/(1.0f + __expf(-(ad1 + qd)));
        float g2 = 1.0f/(1.0f + __expf(-(ad2 + qd)));
        float g3 = 1.0f/(1.0f + __expf(-(ad3 + qd)));
        *reinterpret_cast<float4*>(gate + (size_t)(bn0 + w)*HW + s0 + lane*4)
            = make_float4(g0, g1, g2, g3);

        float l0 = ac0 + qc, l1 = ac1 + qc, l2 = ac2 + qc, l3 = ac3 + qc;
        float m = fmaxf(fmaxf(l0, l1), fmaxf(l2, l3));
        #pragma unroll
        for (int k = 32; k > 0; k >>= 1) m = fmaxf(m, __shfl_xor(m, k));
        float e0 = __expf(l0 - m), e1 = __expf(l1 - m), e2 = __expf(l2 - m), e3 = __expf(l3 - m);
        float z = e0 + e1 + e2 + e3;
        #pragma unroll
        for (int k = 32; k > 0; k >>= 1) z += __shfl_xor(z, k);
        *reinterpret_cast<float4*>(&e_lds[w][lane*4]) = make_float4(e0, e1, e2, e3);
        if (lane == 0) {
            float* mzp = mz + ((size_t)(b*NCH + ch)*NH + w)*2;
            mzp[0] = m; mzp[1] = z;
        }
    }
    __syncthreads();

    // ---- phase 3: partial pool, transposed mapping: thread -> (c, 4 heads), s serial (L2-hot re-read)
    {
        int ng = t >> 8;                 // 0 or 1
        int c  = t & 255;
        const float* vrow = v + ((size_t)(b*DO + c))*HW + s0;
        float a0 = 0.f, a1 = 0.f, a2 = 0.f, a3 = 0.f;
        #pragma unroll 4
        for (int j = 0; j < CHS/4; ++j) {
            float4 v4 = *reinterpret_cast<const float4*>(vrow + j*4);
            float4 e0 = *reinterpret_cast<const float4*>(&e_lds[ng*4+0][j*4]);
            float4 e1 = *reinterpret_cast<const float4*>(&e_lds[ng*4+1][j*4]);
            float4 e2 = *reinterpret_cast<const float4*>(&e_lds[ng*4+2][j*4]);
            float4 e3 = *reinterpret_cast<const float4*>(&e_lds[ng*4+3][j*4]);
            a0 += v4.x*e0.x + v4.y*e0.y + v4.z*e0.z + v4.w*e0.w;
            a1 += v4.x*e1.x + v4.y*e1.y + v4.z*e1.z + v4.w*e1.w;
            a2 += v4.x*e2.x + v4.y*e2.y + v4.z*e2.z + v4.w*e2.w;
            a3 += v4.x*e3.x + v4.y*e3.y + v4.z*e3.z + v4.w*e3.w;
        }
        size_t pb = ((size_t)(b*NCH + ch)*NH + ng*4)*DO + c;
        pvp[pb]        = a0;
        pvp[pb + DO]   = a1;
        pvp[pb + 2*DO] = a2;
        pvp[pb + 3*DO] = a3;
    }
}

// ---------------------------------------------------------------- k4c: softmax-scale combine of 4 chunks + GEMV
__global__ void k4c(const float* __restrict__ pvp, const float* __restrict__ mz,
                    const float* __restrict__ w_v, const float* __restrict__ b_v,
                    float* __restrict__ attn) {
    __shared__ float scale[NCH][NH];
    __shared__ float pv_lds[NH*DO];
    int b = blockIdx.x, t = threadIdx.x;
    if (t < NH) {
        int n = t;
        float M = -1e30f;
        for (int ch = 0; ch < NCH; ++ch)
            M = fmaxf(M, mz[((size_t)(b*NCH+ch)*NH+n)*2]);
        float Z = 0.f;
        for (int ch = 0; ch < NCH; ++ch) {
            float sc = __expf(mz[((size_t)(b*NCH+ch)*NH+n)*2] - M);
            Z += sc * mz[((size_t)(b*NCH+ch)*NH+n)*2 + 1];
            scale[ch][n] = sc;
        }
        float inv = 1.0f/Z;
        for (int ch = 0; ch < NCH; ++ch) scale[ch][n] *= inv;
    }
    __syncthreads();
    // combine with float4 reads: NH*DO = 2048 floats = 512 float4; 256 threads x 2
    #pragma unroll
    for (int r = 0; r < 2; ++r) {
        int i4 = t + r*256;              // float4 index, head = i4/64
        int n  = i4 >> 6;
        float4 s = make_float4(0.f, 0.f, 0.f, 0.f);
        #pragma unroll
        for (int ch = 0; ch < NCH; ++ch) {
            float sc = scale[ch][n];
            float4 p = reinterpret_cast<const float4*>(pvp + (size_t)(b*NCH + ch)*NH*DO)[i4];
            s.x = fmaf(sc, p.x, s.x); s.y = fmaf(sc, p.y, s.y);
            s.z = fmaf(sc, p.z, s.z); s.w = fmaf(sc, p.w, s.w);
        }
        *reinterpret_cast<float4*>(&pv_lds[i4*4]) = s;
    }
    __syncthreads();
    int n = t >> 5;
    float acc = b_v[t];
    const float4* w4 = reinterpret_cast<const float4*>(w_v + t*DO);
    #pragma unroll 4
    for (int c4 = 0; c4 < DO/4; ++c4) {
        float4 wv = w4[c4];
        int c = c4*4;
        acc += pv_lds[n*DO+c]*wv.x + pv_lds[n*DO+c+1]*wv.y + pv_lds[n*DO+c+2]*wv.z + pv_lds[n*DO+c+3]*wv.w;
    }
    attn[b*DO + t] = acc;
}

// ---------------------------------------------------------------- k5: out = leaky(bn(gate[s^T]*attn + v))
__global__ void k5_out(const float* __restrict__ v, const float* __restrict__ gate,
                       const float* __restrict__ attn,
                       const float* __restrict__ bn_g, const float* __restrict__ bn_b,
                       const float* __restrict__ bn_m, const float* __restrict__ bn_v,
                       float* __restrict__ out) {
    int c = blockIdx.x, b = blockIdx.y;
    int n = c >> 5, d = c & 31;
    int t = threadIdx.x;
    __shared__ float g[32*33];             // stride 33 kills transpose bank conflicts
    float4 gv = reinterpret_cast<const float4*>(gate + (b*NH + n)*HW)[t];
    int s0 = t*4;
    int ga = s0 >> 5, gb = s0 & 31;
    g[ga*33 + gb + 0] = gv.x;
    g[ga*33 + gb + 1] = gv.y;
    g[ga*33 + gb + 2] = gv.z;
    g[ga*33 + gb + 3] = gv.w;
    __syncthreads();
    float av   = attn[(b*NH + n)*DH + d];
    float inv  = bn_g[c] / sqrtf(bn_v[c] + 1e-5f);
    float mean = bn_m[c], beta = bn_b[c];
    size_t base = ((size_t)(b*DO + c))*HW;
    float4 r4 = reinterpret_cast<const float4*>(v + base)[t];
    int l = 4*t;
    int i_ = l >> 5, j_ = l & 31;          // gate index s = j*32 + i
    float x0 = g[(j_+0)*33 + i_]*av + r4.x;
    float x1 = g[(j_+1)*33 + i_]*av + r4.y;
    float x2 = g[(j_+2)*33 + i_]*av + r4.z;
    float x3 = g[(j_+3)*33 + i_]*av + r4.w;
    float y0 = (x0 - mean)*inv + beta; y0 = y0 >= 0.f ? y0 : 0.1f*y0;
    float y1 = (x1 - mean)*inv + beta; y1 = y1 >= 0.f ? y1 : 0.1f*y1;
    float y2 = (x2 - mean)*inv + beta; y2 = y2 >= 0.f ? y2 : 0.1f*y2;
    float y3 = (x3 - mean)*inv + beta; y3 = y3 >= 0.f ? y3 : 0.1f*y3;
    reinterpret_cast<float4*>(out + base)[t] = make_float4(y0, y1, y2, y3);
}

// ----------------------------------------------------------------
extern "C" void kernel_launch(void* const* d_in, const int* in_sizes, int n_in,
                              void* d_out, int out_size, void* d_ws, size_t ws_size,
                              hipStream_t stream) {
    const float* q      = (const float*)d_in[0];
    const float* v      = (const float*)d_in[1];
    const float* w_q    = (const float*)d_in[2];
    const float* b_q    = (const float*)d_in[3];
    const float* w_kc   = (const float*)d_in[4];
    const float* b_kc   = (const float*)d_in[5];
    const float* w_kd   = (const float*)d_in[6];
    const float* b_kd   = (const float*)d_in[7];
    const float* w_v    = (const float*)d_in[8];
    const float* b_v    = (const float*)d_in[9];
    const float* temp_c = (const float*)d_in[10];
    const float* temp_d = (const float*)d_in[11];
    const float* bn_g   = (const float*)d_in[12];
    const float* bn_b   = (const float*)d_in[13];
    const float* bn_m   = (const float*)d_in[14];
    const float* bn_v   = (const float*)d_in[15];
    float* out = (float*)d_out;

    float* ws   = (float*)d_ws;
    float* qv   = ws;                     // B*DO         = 16384
    float* wqkc = qv   + B*DO;            // B*NH*DO      = 131072
    float* wqkd = wqkc + B*NH*DO;         // 131072
    float* qbc  = wqkd + B*NH*DO;         // 512
    float* qbd  = qbc  + B*NH;            // 512
    float* gate = qbd  + B*NH;            // B*NH*HW      = 524288
    float* mz   = gate + B*NH*HW;         // B*NCH*NH*2   = 4096
    float* pvp  = mz   + B*NCH*NH*2;      // B*NCH*NH*DO  = 524288
    float* attn = pvp  + B*NCH*NH*DO;     // B*DO         = 16384

    k1_qv <<<dim3(16, B),    256, 0, stream>>>(q, w_q, b_q, qv);
    k2_wqk<<<B*NH,           256, 0, stream>>>(qv, w_kc, b_kc, w_kd, b_kd, temp_c, temp_d,
                                               wqkc, wqkd, qbc, qbd);
    k3g   <<<dim3(NCH, B),   512, 0, stream>>>(v, wqkc, wqkd, qbc, qbd, gate, pvp, mz);
    k4c   <<<B,              256, 0, stream>>>(pvp, mz, w_v, b_v, attn);
    k5_out<<<dim3(DO, B),    256, 0, stream>>>(v, gate, attn, bn_g, bn_b, bn_m, bn_v, out);
}

// Round 10
// 77.410 us; speedup vs baseline: 1.4812x; 1.0710x over previous
//
#include <hip/hip_runtime.h>
#include <math.h>

#define B    64
#define DQ   512
#define DO   256
#define NH   8
#define DH   32
#define HW   1024
#define NCH  8      // s-chunks per image
#define CHS  128    // s per chunk

// ---------------------------------------------------------------- k1: qv = q @ w_q.T + b_q   (wave-per-output GEMV)
__global__ __launch_bounds__(256) void k1_qv(const float* __restrict__ q,
                                             const float* __restrict__ w_q,
                                             const float* __restrict__ b_q,
                                             float* __restrict__ qv) {
    int cg = blockIdx.x, b = blockIdx.y;
    int t = threadIdx.x;
    int wid = t >> 6, lane = t & 63;
    const float4* qrow = reinterpret_cast<const float4*>(q + (size_t)b*DQ);
    float4 q0 = qrow[lane*2], q1 = qrow[lane*2 + 1];
    #pragma unroll
    for (int r = 0; r < 4; ++r) {
        int c = cg*16 + wid*4 + r;
        const float4* wrow = reinterpret_cast<const float4*>(w_q + (size_t)c*DQ);
        float4 w0 = wrow[lane*2], w1 = wrow[lane*2 + 1];
        float acc = q0.x*w0.x + q0.y*w0.y + q0.z*w0.z + q0.w*w0.w
                  + q1.x*w1.x + q1.y*w1.y + q1.z*w1.z + q1.w*w1.w;
        #pragma unroll
        for (int k = 32; k > 0; k >>= 1) acc += __shfl_xor(acc, k);
        if (lane == 0) qv[b*DO + c] = acc + b_q[c];
    }
}

// ---------------------------------------------------------------- k2: fold qv into kc/kd weights
__global__ void k2_wqk(const float* __restrict__ qv,
                       const float* __restrict__ w_kc, const float* __restrict__ b_kc,
                       const float* __restrict__ w_kd, const float* __restrict__ b_kd,
                       const float* __restrict__ temp_c, const float* __restrict__ temp_d,
                       float* __restrict__ wqkc, float* __restrict__ wqkd,
                       float* __restrict__ qbc, float* __restrict__ qbd) {
    int bn = blockIdx.x;              // b*8 + n
    int n  = bn & 7;
    int t  = threadIdx.x;             // c
    __shared__ float qvs[DH];
    if (t < DH) qvs[t] = qv[(bn >> 3)*DO + n*DH + t];
    __syncthreads();
    float itc = 1.0f / temp_c[0];
    float itd = 1.0f / temp_d[0];
    float ac = 0.f, ad = 0.f;
    #pragma unroll
    for (int d = 0; d < DH; ++d) {
        float qd = qvs[d];
        ac += qd * w_kc[(n*DH + d)*DO + t];
        ad += qd * w_kd[(n*DH + d)*DO + t];
    }
    wqkc[bn*DO + t] = ac * itc;
    wqkd[bn*DO + t] = ad * itd;
    if (t == 0) {
        float sc = 0.f;
        for (int d = 0; d < DH; ++d) sc += qvs[d]*b_kc[n*DH + d];
        qbc[bn] = sc * itc;
    }
    if (t == 1) {
        float sd = 0.f;
        for (int d = 0; d < DH; ++d) sd += qvs[d]*b_kd[n*DH + d];
        qbd[bn] = sd * itd;
    }
}

// ---------------------------------------------------------------- k3h: logits + gate + wave-local softmax + pool
// grid (NCH=8, B) = 512 blocks (2/CU), block 512 (8 waves), 16 waves/CU.
// Phase 1: wave csub owns 32 channels, computes partials for ALL 8 heads (c+d)
//          in registers; lanes hold 2 s (float2 loads). 32 loads/wave total.
__global__ __launch_bounds__(512, 4)
void k3h(const float* __restrict__ v,
         const float* __restrict__ wqkc, const float* __restrict__ wqkd,
         const float* __restrict__ qbc,  const float* __restrict__ qbd,
         float* __restrict__ gate, float* __restrict__ pvp, float* __restrict__ mz) {
    __shared__ float pc[8*NH*CHS];       // 32 KB collect partials [csub][n][s]
    __shared__ float pd[8*NH*CHS];       // 32 KB diffuse partials
    __shared__ float e_lds[NH][CHS];     // 4 KB
    int ch = blockIdx.x, b = blockIdx.y;
    int t  = threadIdx.x;
    int s0 = ch*CHS;
    int bn0 = b*NH;
    int lane = t & 63;
    int sl2  = lane*2;
    int csub = __builtin_amdgcn_readfirstlane(t >> 6);

    // ---- phase 1: one v pass; both collect+diffuse partials in regs
    {
        const float* vb = v + (size_t)b*DO*HW + s0 + sl2;
        const float* wc = wqkc + (size_t)bn0*DO;
        const float* wd = wqkd + (size_t)bn0*DO;
        float acc_c0[NH] = {0,0,0,0,0,0,0,0}, acc_c1[NH] = {0,0,0,0,0,0,0,0};
        float acc_d0[NH] = {0,0,0,0,0,0,0,0}, acc_d1[NH] = {0,0,0,0,0,0,0,0};
        int cbase = csub*32;
        #pragma unroll 8
        for (int cc = 0; cc < 32; ++cc) {
            int c = cbase + cc;
            float2 v2 = *reinterpret_cast<const float2*>(vb + (size_t)c*HW);
            #pragma unroll
            for (int n = 0; n < NH; ++n) {
                float wcv = wc[n*DO + c];     // wave-uniform -> scalar load
                float wdv = wd[n*DO + c];
                acc_c0[n] = fmaf(wcv, v2.x, acc_c0[n]);
                acc_c1[n] = fmaf(wcv, v2.y, acc_c1[n]);
                acc_d0[n] = fmaf(wdv, v2.x, acc_d0[n]);
                acc_d1[n] = fmaf(wdv, v2.y, acc_d1[n]);
            }
        }
        #pragma unroll
        for (int n = 0; n < NH; ++n) {
            *reinterpret_cast<float2*>(&pc[(csub*NH + n)*CHS + sl2]) = make_float2(acc_c0[n], acc_c1[n]);
            *reinterpret_cast<float2*>(&pd[(csub*NH + n)*CHS + sl2]) = make_float2(acc_d0[n], acc_d1[n]);
        }
    }
    __syncthreads();

    // ---- phase 2: wave n combines csub partials for head n; softmax + gate, all wave-local
    {
        int n = csub;
        float lc0 = qbc[bn0+n], lc1 = lc0;
        float ld0 = qbd[bn0+n], ld1 = ld0;
        #pragma unroll
        for (int k = 0; k < 8; ++k) {
            float2 c2 = *reinterpret_cast<const float2*>(&pc[(k*NH + n)*CHS + sl2]);
            float2 d2 = *reinterpret_cast<const float2*>(&pd[(k*NH + n)*CHS + sl2]);
            lc0 += c2.x; lc1 += c2.y;
            ld0 += d2.x; ld1 += d2.y;
        }
        float g0 = 1.0f/(1.0f + __expf(-ld0));
        float g1 = 1.0f/(1.0f + __expf(-ld1));
        *reinterpret_cast<float2*>(gate + (size_t)(bn0+n)*HW + s0 + sl2) = make_float2(g0, g1);

        float m = fmaxf(lc0, lc1);
        #pragma unroll
        for (int k = 32; k > 0; k >>= 1) m = fmaxf(m, __shfl_xor(m, k));
        float e0 = __expf(lc0 - m), e1 = __expf(lc1 - m);
        float z = e0 + e1;
        #pragma unroll
        for (int k = 32; k > 0; k >>= 1) z += __shfl_xor(z, k);
        *reinterpret_cast<float2*>(&e_lds[n][sl2]) = make_float2(e0, e1);
        if (lane == 0) {
            float* mzp = mz + ((size_t)(b*NCH + ch)*NH + n)*2;
            mzp[0] = m; mzp[1] = z;
        }
    }
    __syncthreads();

    // ---- phase 3: partial pool, transposed mapping: thread -> (c, 4 heads), s serial (L1/L2-hot)
    {
        int ng = t >> 8;                 // 0 or 1
        int c  = t & 255;
        const float* vrow = v + ((size_t)(b*DO + c))*HW + s0;
        float a0 = 0.f, a1 = 0.f, a2 = 0.f, a3 = 0.f;
        #pragma unroll 4
        for (int j = 0; j < CHS/4; ++j) {
            float4 v4 = *reinterpret_cast<const float4*>(vrow + j*4);
            float4 e0 = *reinterpret_cast<const float4*>(&e_lds[ng*4+0][j*4]);
            float4 e1 = *reinterpret_cast<const float4*>(&e_lds[ng*4+1][j*4]);
            float4 e2 = *reinterpret_cast<const float4*>(&e_lds[ng*4+2][j*4]);
            float4 e3 = *reinterpret_cast<const float4*>(&e_lds[ng*4+3][j*4]);
            a0 += v4.x*e0.x + v4.y*e0.y + v4.z*e0.z + v4.w*e0.w;
            a1 += v4.x*e1.x + v4.y*e1.y + v4.z*e1.z + v4.w*e1.w;
            a2 += v4.x*e2.x + v4.y*e2.y + v4.z*e2.z + v4.w*e2.w;
            a3 += v4.x*e3.x + v4.y*e3.y + v4.z*e3.z + v4.w*e3.w;
        }
        size_t pb = ((size_t)(b*NCH + ch)*NH + ng*4)*DO + c;
        pvp[pb]        = a0;
        pvp[pb + DO]   = a1;
        pvp[pb + 2*DO] = a2;
        pvp[pb + 3*DO] = a3;
    }
}

// ---------------------------------------------------------------- k4c: softmax-scale combine of 8 chunks + GEMV
__global__ void k4c(const float* __restrict__ pvp, const float* __restrict__ mz,
                    const float* __restrict__ w_v, const float* __restrict__ b_v,
                    float* __restrict__ attn) {
    __shared__ float scale[NCH][NH];
    __shared__ float pv_lds[NH*DO];
    int b = blockIdx.x, t = threadIdx.x;
    if (t < NH) {
        int n = t;
        float M = -1e30f;
        for (int ch = 0; ch < NCH; ++ch)
            M = fmaxf(M, mz[((size_t)(b*NCH+ch)*NH+n)*2]);
        float Z = 0.f;
        for (int ch = 0; ch < NCH; ++ch) {
            float sc = __expf(mz[((size_t)(b*NCH+ch)*NH+n)*2] - M);
            Z += sc * mz[((size_t)(b*NCH+ch)*NH+n)*2 + 1];
            scale[ch][n] = sc;
        }
        float inv = 1.0f/Z;
        for (int ch = 0; ch < NCH; ++ch) scale[ch][n] *= inv;
    }
    __syncthreads();
    #pragma unroll
    for (int r = 0; r < 2; ++r) {
        int i4 = t + r*256;              // float4 index, head = i4/64
        int n  = i4 >> 6;
        float4 s = make_float4(0.f, 0.f, 0.f, 0.f);
        #pragma unroll
        for (int ch = 0; ch < NCH; ++ch) {
            float sc = scale[ch][n];
            float4 p = reinterpret_cast<const float4*>(pvp + (size_t)(b*NCH + ch)*NH*DO)[i4];
            s.x = fmaf(sc, p.x, s.x); s.y = fmaf(sc, p.y, s.y);
            s.z = fmaf(sc, p.z, s.z); s.w = fmaf(sc, p.w, s.w);
        }
        *reinterpret_cast<float4*>(&pv_lds[i4*4]) = s;
    }
    __syncthreads();
    int n = t >> 5;
    float acc = b_v[t];
    const float4* w4 = reinterpret_cast<const float4*>(w_v + t*DO);
    #pragma unroll 4
    for (int c4 = 0; c4 < DO/4; ++c4) {
        float4 wv = w4[c4];
        int c = c4*4;
        acc += pv_lds[n*DO+c]*wv.x + pv_lds[n*DO+c+1]*wv.y + pv_lds[n*DO+c+2]*wv.z + pv_lds[n*DO+c+3]*wv.w;
    }
    attn[b*DO + t] = acc;
}

// ---------------------------------------------------------------- k5: out = leaky(bn(gate[s^T]*attn + v))
__global__ void k5_out(const float* __restrict__ v, const float* __restrict__ gate,
                       const float* __restrict__ attn,
                       const float* __restrict__ bn_g, const float* __restrict__ bn_b,
                       const float* __restrict__ bn_m, const float* __restrict__ bn_v,
                       float* __restrict__ out) {
    int c = blockIdx.x, b = blockIdx.y;
    int n = c >> 5, d = c & 31;
    int t = threadIdx.x;
    __shared__ float g[32*33];             // stride 33 kills transpose bank conflicts
    float4 gv = reinterpret_cast<const float4*>(gate + (b*NH + n)*HW)[t];
    int s0 = t*4;
    int ga = s0 >> 5, gb = s0 & 31;
    g[ga*33 + gb + 0] = gv.x;
    g[ga*33 + gb + 1] = gv.y;
    g[ga*33 + gb + 2] = gv.z;
    g[ga*33 + gb + 3] = gv.w;
    __syncthreads();
    float av   = attn[(b*NH + n)*DH + d];
    float inv  = bn_g[c] / sqrtf(bn_v[c] + 1e-5f);
    float mean = bn_m[c], beta = bn_b[c];
    size_t base = ((size_t)(b*DO + c))*HW;
    float4 r4 = reinterpret_cast<const float4*>(v + base)[t];
    int l = 4*t;
    int i_ = l >> 5, j_ = l & 31;          // gate index s = j*32 + i
    float x0 = g[(j_+0)*33 + i_]*av + r4.x;
    float x1 = g[(j_+1)*33 + i_]*av + r4.y;
    float x2 = g[(j_+2)*33 + i_]*av + r4.z;
    float x3 = g[(j_+3)*33 + i_]*av + r4.w;
    float y0 = (x0 - mean)*inv + beta; y0 = y0 >= 0.f ? y0 : 0.1f*y0;
    float y1 = (x1 - mean)*inv + beta; y1 = y1 >= 0.f ? y1 : 0.1f*y1;
    float y2 = (x2 - mean)*inv + beta; y2 = y2 >= 0.f ? y2 : 0.1f*y2;
    float y3 = (x3 - mean)*inv + beta; y3 = y3 >= 0.f ? y3 : 0.1f*y3;
    reinterpret_cast<float4*>(out + base)[t] = make_float4(y0, y1, y2, y3);
}

// ----------------------------------------------------------------
extern "C" void kernel_launch(void* const* d_in, const int* in_sizes, int n_in,
                              void* d_out, int out_size, void* d_ws, size_t ws_size,
                              hipStream_t stream) {
    const float* q      = (const float*)d_in[0];
    const float* v      = (const float*)d_in[1];
    const float* w_q    = (const float*)d_in[2];
    const float* b_q    = (const float*)d_in[3];
    const float* w_kc   = (const float*)d_in[4];
    const float* b_kc   = (const float*)d_in[5];
    const float* w_kd   = (const float*)d_in[6];
    const float* b_kd   = (const float*)d_in[7];
    const float* w_v    = (const float*)d_in[8];
    const float* b_v    = (const float*)d_in[9];
    const float* temp_c = (const float*)d_in[10];
    const float* temp_d = (const float*)d_in[11];
    const float* bn_g   = (const float*)d_in[12];
    const float* bn_b   = (const float*)d_in[13];
    const float* bn_m   = (const float*)d_in[14];
    const float* bn_v   = (const float*)d_in[15];
    float* out = (float*)d_out;

    float* ws   = (float*)d_ws;
    float* qv   = ws;                     // B*DO         = 16384
    float* wqkc = qv   + B*DO;            // B*NH*DO      = 131072
    float* wqkd = wqkc + B*NH*DO;         // 131072
    float* qbc  = wqkd + B*NH*DO;         // 512
    float* qbd  = qbc  + B*NH;            // 512
    float* gate = qbd  + B*NH;            // B*NH*HW      = 524288
    float* mz   = gate + B*NH*HW;         // B*NCH*NH*2   = 8192
    float* pvp  = mz   + B*NCH*NH*2;      // B*NCH*NH*DO  = 1048576
    float* attn = pvp  + B*NCH*NH*DO;     // B*DO         = 16384

    k1_qv <<<dim3(16, B),    256, 0, stream>>>(q, w_q, b_q, qv);
    k2_wqk<<<B*NH,           256, 0, stream>>>(qv, w_kc, b_kc, w_kd, b_kd, temp_c, temp_d,
                                               wqkc, wqkd, qbc, qbd);
    k3h   <<<dim3(NCH, B),   512, 0, stream>>>(v, wqkc, wqkd, qbc, qbd, gate, pvp, mz);
    k4c   <<<B,              256, 0, stream>>>(pvp, mz, w_v, b_v, attn);
    k5_out<<<dim3(DO, B),    256, 0, stream>>>(v, gate, attn, bn_g, bn_b, bn_m, bn_v, out);
}